// Round 6
// baseline (1208.419 us; speedup 1.0000x reference)
//
#include <hip/hip_runtime.h>
#include <math.h>

#define D 128
#define CSH 13   // src-chunk shift: 8192 nodes/chunk -> 7 chunks at N=50000

// ---------------- preprocessing ----------------

// deg2[dst*nchunk + (src>>CSH)] ++
__global__ __launch_bounds__(256) void count_kernel(
    const int* __restrict__ src, const int* __restrict__ dst,
    int* __restrict__ deg2, int E, int nchunk)
{
    int e = blockIdx.x * 256 + threadIdx.x;
    if (e < E) {
        int c = src[e] >> CSH;
        atomicAdd(&deg2[(size_t)dst[e] * nchunk + c], 1);
    }
}

// row_off = exclusive scan of row-sums of deg2; cursor2 = per-(row,chunk) bases
__global__ __launch_bounds__(1024) void scan_kernel(
    const int* __restrict__ deg2, int* __restrict__ row_off,
    int* __restrict__ cursor2, int n, int nchunk)
{
    __shared__ int wsum[16];
    int tid  = threadIdx.x;
    int lane = tid & 63;
    int wid  = tid >> 6;
    int carry = 0;
    for (int base = 0; base < n; base += 1024) {
        int i = base + tid;
        int v = 0;
        if (i < n)
            for (int c = 0; c < nchunk; ++c) v += deg2[(size_t)i * nchunk + c];
        int x = v;
        #pragma unroll
        for (int off = 1; off < 64; off <<= 1) {
            int t = __shfl_up(x, off);
            if (lane >= off) x += t;
        }
        __syncthreads();
        if (lane == 63) wsum[wid] = x;
        __syncthreads();
        if (tid < 16) {
            int y = wsum[tid];
            #pragma unroll
            for (int off = 1; off < 16; off <<= 1) {
                int t = __shfl_up(y, off, 16);
                if (tid >= off) y += t;
            }
            wsum[tid] = y;
        }
        __syncthreads();
        int wexcl = wid ? wsum[wid - 1] : 0;
        int excl  = carry + wexcl + x - v;
        if (i < n) {
            row_off[i] = excl;
            int p = excl;
            for (int c = 0; c < nchunk; ++c) {
                cursor2[(size_t)i * nchunk + c] = p;
                p += deg2[(size_t)i * nchunk + c];
            }
        }
        carry += wsum[15];
    }
    if (tid == 0) row_off[n] = carry;
}

// single pass: edges land grouped by (dst row, src chunk)
__global__ __launch_bounds__(256) void scatter_kernel(
    const int* __restrict__ src, const int* __restrict__ dst,
    const float* __restrict__ ew, int* __restrict__ cursor2,
    int2* __restrict__ edge_s, int E, int nchunk)
{
    int e = blockIdx.x * 256 + threadIdx.x;
    if (e < E) {
        int s = src[e];
        int pos = atomicAdd(&cursor2[(size_t)dst[e] * nchunk + (s >> CSH)], 1);
        edge_s[pos] = make_int2(s, __float_as_int(ew[e]));
    }
}

// sdeg[i] = sum of ew over row i
__global__ __launch_bounds__(256) void sdeg_kernel(
    const int* __restrict__ row_off, const int2* __restrict__ edge_s,
    float* __restrict__ sdeg, int N)
{
    int lane = threadIdx.x & 63;
    int node = blockIdx.x * 4 + (threadIdx.x >> 6);
    if (node >= N) return;
    int beg = row_off[node], end = row_off[node + 1];
    float s = 0.f;
    for (int e = beg + lane; e < end; e += 64)
        s += __int_as_float(edge_s[e].y);
    #pragma unroll
    for (int off = 32; off; off >>= 1) s += __shfl_xor(s, off);
    if (lane == 0) sdeg[node] = s;
}

// ---------------- fused 3-matmul per layer (single k-sweep) ----------------
// aA/aB[n] = halves of (W1 h[n] + b1);  base = (W3 h + b3) - s*(W2 h)
// 256 threads, 32 nodes/block. tn=tid&7 (4 nodes), to=tid>>3 (4 outs).
// Per thread: acc[3][4][4]. Per 4-k chunk: 192 FMA vs 4 LDS b128 + 12 W
// float4 (ping-pong double-buffered a full chunk ahead).

__global__ __launch_bounds__(256, 2) void gemm_kernel(
    const float* __restrict__ in, const float* __restrict__ W1,
    const float* __restrict__ b1, const float* __restrict__ W2,
    const float* __restrict__ W3, const float* __restrict__ b3,
    const float* __restrict__ sdeg, float* __restrict__ aA,
    float* __restrict__ aB, float* __restrict__ base_out, int N)
{
    __shared__ float Hs[128][36];   // [k][node], padded

    int tid = threadIdx.x;
    int tn  = tid & 7;         // 8 node-threads x 4 nodes = 32
    int to  = tid >> 3;        // 32 out-threads x 4 outs = 128
    int n0  = blockIdx.x * 32;
    int o0  = to * 4;

    // stage H transposed; r-inner order => conflict-free LDS writes
    for (int idx = tid; idx < 1024; idx += 256) {
        int r  = idx & 31;
        int c4 = idx >> 5;
        float4 v = make_float4(0.f, 0.f, 0.f, 0.f);
        if (n0 + r < N)
            v = *(const float4*)&in[(size_t)(n0 + r) * D + c4 * 4];
        Hs[c4 * 4 + 0][r] = v.x;
        Hs[c4 * 4 + 1][r] = v.y;
        Hs[c4 * 4 + 2][r] = v.z;
        Hs[c4 * 4 + 3][r] = v.w;
    }
    __syncthreads();           // ONLY barrier

    const float* Wm[3] = {W1, W2, W3};

    auto loadW = [&](int kc, float4 (&w)[3][4]) {
        #pragma unroll
        for (int m = 0; m < 3; ++m)
            #pragma unroll
            for (int j = 0; j < 4; ++j)
                w[m][j] = *(const float4*)&Wm[m][(size_t)(o0 + j) * D + kc];
    };

    float acc[3][4][4];
    #pragma unroll
    for (int m = 0; m < 3; ++m)
        #pragma unroll
        for (int i = 0; i < 4; ++i)
            #pragma unroll
            for (int j = 0; j < 4; ++j) acc[m][i][j] = 0.f;

    auto fmas = [&](int kc, const float4 (&w)[3][4]) {
        float4 hv[4];
        #pragma unroll
        for (int kk = 0; kk < 4; ++kk)
            hv[kk] = *(const float4*)&Hs[kc + kk][tn * 4];
        #pragma unroll
        for (int kk = 0; kk < 4; ++kk) {
            float hh[4] = {hv[kk].x, hv[kk].y, hv[kk].z, hv[kk].w};
            #pragma unroll
            for (int m = 0; m < 3; ++m)
                #pragma unroll
                for (int j = 0; j < 4; ++j) {
                    float wf = ((const float*)&w[m][j])[kk];
                    #pragma unroll
                    for (int i = 0; i < 4; ++i)
                        acc[m][i][j] = fmaf(hh[i], wf, acc[m][i][j]);
                }
        }
    };

    float4 wA[3][4], wB[3][4];
    loadW(0, wA);
    for (int kc = 0; kc < D; kc += 8) {
        loadW(kc + 4, wB);
        fmas(kc, wA);
        if (kc + 8 < D) loadW(kc + 8, wA);
        fmas(kc + 4, wB);
    }

    // ---- epilogue ----
    float4 b1v = *(const float4*)&b1[o0];
    float4 b3v = *(const float4*)&b3[o0];
    float bf1[4] = {b1v.x, b1v.y, b1v.z, b1v.w};
    float bf3[4] = {b3v.x, b3v.y, b3v.z, b3v.w};
    float* ah = (o0 < 64) ? aA : aB;
    int    oh = o0 & 63;

    #pragma unroll
    for (int i = 0; i < 4; ++i) {
        int row = n0 + tn * 4 + i;
        if (row < N) {
            float sv = sdeg[row];
            float4 av = make_float4(acc[0][i][0] + bf1[0], acc[0][i][1] + bf1[1],
                                    acc[0][i][2] + bf1[2], acc[0][i][3] + bf1[3]);
            float4 bv = make_float4(acc[2][i][0] + bf3[0] - sv * acc[1][i][0],
                                    acc[2][i][1] + bf3[1] - sv * acc[1][i][1],
                                    acc[2][i][2] + bf3[2] - sv * acc[1][i][2],
                                    acc[2][i][3] + bf3[3] - sv * acc[1][i][3]);
            *(float4*)&ah[(size_t)row * 64 + oh]      = av;
            *(float4*)&base_out[(size_t)row * D + o0] = bv;
        }
    }
}

// ---------------- CSR aggregate + activation (one 64-feature half) ------

__global__ __launch_bounds__(256) void agg_kernel(
    const float* __restrict__ aH, const float* __restrict__ base,
    const int* __restrict__ row_off, const int2* __restrict__ edge_s,
    float* __restrict__ out, int N, int hofs, int last)
{
    int lane = threadIdx.x & 63;
    int node = blockIdx.x * 4 + (threadIdx.x >> 6);
    if (node >= N) return;

    float acc = base[(size_t)node * D + hofs + lane];
    int beg = row_off[node];
    int end = row_off[node + 1];

    int e = beg;
    if ((e & 1) && e < end) {         // peel to align int4 batches
        int2 ed = edge_s[e];
        acc = fmaf(__int_as_float(ed.y), aH[(size_t)ed.x * 64 + lane], acc);
        ++e;
    }
    for (; e + 16 <= end; e += 16) {  // 16 edges, 8 aligned int4 loads
        int4 ed[8];
        #pragma unroll
        for (int i = 0; i < 8; ++i) ed[i] = *(const int4*)&edge_s[e + i * 2];
        float v[16];
        #pragma unroll
        for (int i = 0; i < 8; ++i) {
            v[2 * i]     = aH[(size_t)ed[i].x * 64 + lane];
            v[2 * i + 1] = aH[(size_t)ed[i].z * 64 + lane];
        }
        #pragma unroll
        for (int i = 0; i < 8; ++i) {
            acc = fmaf(__int_as_float(ed[i].y), v[2 * i], acc);
            acc = fmaf(__int_as_float(ed[i].w), v[2 * i + 1], acc);
        }
    }
    for (; e + 4 <= end; e += 4) {
        int4 e0 = *(const int4*)&edge_s[e];
        int4 e1 = *(const int4*)&edge_s[e + 2];
        float v0 = aH[(size_t)e0.x * 64 + lane];
        float v1 = aH[(size_t)e0.z * 64 + lane];
        float v2 = aH[(size_t)e1.x * 64 + lane];
        float v3 = aH[(size_t)e1.z * 64 + lane];
        acc = fmaf(__int_as_float(e0.y), v0, acc);
        acc = fmaf(__int_as_float(e0.w), v1, acc);
        acc = fmaf(__int_as_float(e1.y), v2, acc);
        acc = fmaf(__int_as_float(e1.w), v3, acc);
    }
    for (; e < end; ++e) {
        int2 ed = edge_s[e];
        acc = fmaf(__int_as_float(ed.y), aH[(size_t)ed.x * 64 + lane], acc);
    }

    acc = acc >= 0.f ? acc : 0.1f * acc;          // leaky relu 0.1
    if (last) acc = 1.f / (1.f + __expf(-acc));   // sigmoid
    out[(size_t)node * D + hofs + lane] = acc;
}

// ---------------- launch ----------------

extern "C" void kernel_launch(void* const* d_in, const int* in_sizes, int n_in,
                              void* d_out, int out_size, void* d_ws, size_t ws_size,
                              hipStream_t stream) {
    const float* x   = (const float*)d_in[0];
    const int*   ei  = (const int*)d_in[1];
    const float* ew  = (const float*)d_in[2];
    const float* iW1 = (const float*)d_in[3];
    const float* ib1 = (const float*)d_in[4];
    const float* iW2 = (const float*)d_in[5];
    const float* iW3 = (const float*)d_in[6];
    const float* ib3 = (const float*)d_in[7];
    const float* mW1 = (const float*)d_in[8];
    const float* mb1 = (const float*)d_in[9];
    const float* mW2 = (const float*)d_in[10];
    const float* mW3 = (const float*)d_in[11];
    const float* mb3 = (const float*)d_in[12];
    const float* oW1 = (const float*)d_in[13];
    const float* ob1 = (const float*)d_in[14];
    const float* oW2 = (const float*)d_in[15];
    const float* oW3 = (const float*)d_in[16];
    const float* ob3 = (const float*)d_in[17];

    int N = in_sizes[0] / D;
    int E = in_sizes[2];
    const int* src = ei;
    const int* dst = ei + E;
    int nchunk = (N + (1 << CSH) - 1) >> CSH;

    char* wsp = (char*)d_ws;
    size_t off = 0;
    auto alloc = [&](size_t bytes) -> void* {
        void* p = wsp + off;
        off += (bytes + 255) & ~(size_t)255;
        return p;
    };
    float* h       = (float*)alloc((size_t)N * D * 4);
    float* base    = (float*)alloc((size_t)N * D * 4);
    float* aA      = (float*)alloc((size_t)N * 64 * 4);
    float* aB      = (float*)alloc((size_t)N * 64 * 4);
    float* sdeg    = (float*)alloc((size_t)N * 4);
    int*   deg2    = (int*)alloc((size_t)N * nchunk * 4);
    int*   cursor2 = (int*)alloc((size_t)N * nchunk * 4);
    int*   row_off = (int*)alloc((size_t)(N + 1) * 4);
    int2*  edge_s  = (int2*)alloc((size_t)E * 8);

    hipMemsetAsync(deg2, 0, (size_t)N * nchunk * 4, stream);

    int eblocks = (E + 255) / 256;
    int ablocks = (N + 3) / 4;
    int gblocks = (N + 31) / 32;

    count_kernel<<<eblocks, 256, 0, stream>>>(src, dst, deg2, E, nchunk);
    scan_kernel<<<1, 1024, 0, stream>>>(deg2, row_off, cursor2, N, nchunk);
    scatter_kernel<<<eblocks, 256, 0, stream>>>(src, dst, ew, cursor2, edge_s, E, nchunk);
    sdeg_kernel<<<ablocks, 256, 0, stream>>>(row_off, edge_s, sdeg, N);

    // layer 1 (in): reads x
    gemm_kernel<<<gblocks, 256, 0, stream>>>(x, iW1, ib1, iW2, iW3, ib3, sdeg, aA, aB, base, N);
    agg_kernel<<<ablocks, 256, 0, stream>>>(aA, base, row_off, edge_s, h, N, 0, 0);
    agg_kernel<<<ablocks, 256, 0, stream>>>(aB, base, row_off, edge_s, h, N, 64, 0);
    // layers 2..3 (mid, shared weights)
    for (int l = 0; l < 2; ++l) {
        gemm_kernel<<<gblocks, 256, 0, stream>>>(h, mW1, mb1, mW2, mW3, mb3, sdeg, aA, aB, base, N);
        agg_kernel<<<ablocks, 256, 0, stream>>>(aA, base, row_off, edge_s, h, N, 0, 0);
        agg_kernel<<<ablocks, 256, 0, stream>>>(aB, base, row_off, edge_s, h, N, 64, 0);
    }
    // layer 4 (out) -> d_out with sigmoid
    gemm_kernel<<<gblocks, 256, 0, stream>>>(h, oW1, ob1, oW2, oW3, ob3, sdeg, aA, aB, base, N);
    agg_kernel<<<ablocks, 256, 0, stream>>>(aA, base, row_off, edge_s, (float*)d_out, N, 0, 1);
    agg_kernel<<<ablocks, 256, 0, stream>>>(aB, base, row_off, edge_s, (float*)d_out, N, 64, 1);
}

// Round 7
// 1050.699 us; speedup vs baseline: 1.1501x; 1.1501x over previous
//
#include <hip/hip_runtime.h>
#include <math.h>

#define D 128
#define CSH 13   // src-chunk shift: 8192 nodes/chunk -> 7 chunks at N=50000

// ---------------- preprocessing ----------------

// deg2[dst*nchunk + (src>>CSH)] ++
__global__ __launch_bounds__(256) void count_kernel(
    const int* __restrict__ src, const int* __restrict__ dst,
    int* __restrict__ deg2, int E, int nchunk)
{
    int e = blockIdx.x * 256 + threadIdx.x;
    if (e < E) {
        int c = src[e] >> CSH;
        atomicAdd(&deg2[(size_t)dst[e] * nchunk + c], 1);
    }
}

__global__ __launch_bounds__(256) void rowsum_kernel(
    const int* __restrict__ deg2, int* __restrict__ deg, int N, int nchunk)
{
    int i = blockIdx.x * 256 + threadIdx.x;
    if (i < N) {
        int s = 0;
        for (int c = 0; c < nchunk; ++c) s += deg2[(size_t)i * nchunk + c];
        deg[i] = s;
    }
}

// exclusive scan of deg (small: N ints, single block, shuffle-based)
__global__ __launch_bounds__(1024) void scan_kernel(
    const int* __restrict__ deg, int* __restrict__ row_off, int n)
{
    __shared__ int wsum[16];
    int tid  = threadIdx.x;
    int lane = tid & 63;
    int wid  = tid >> 6;
    int carry = 0;
    for (int base = 0; base < n; base += 1024) {
        int i = base + tid;
        int v = (i < n) ? deg[i] : 0;
        int x = v;
        #pragma unroll
        for (int off = 1; off < 64; off <<= 1) {
            int t = __shfl_up(x, off);
            if (lane >= off) x += t;
        }
        __syncthreads();
        if (lane == 63) wsum[wid] = x;
        __syncthreads();
        if (tid < 16) {
            int y = wsum[tid];
            #pragma unroll
            for (int off = 1; off < 16; off <<= 1) {
                int t = __shfl_up(y, off, 16);
                if (tid >= off) y += t;
            }
            wsum[tid] = y;
        }
        __syncthreads();
        int wexcl = wid ? wsum[wid - 1] : 0;
        int excl  = carry + wexcl + x - v;
        if (i < n) row_off[i] = excl;
        carry += wsum[15];
    }
    if (tid == 0) row_off[n] = carry;
}

// cursor2[i*nchunk+c] = row_off[i] + prefix of deg2 within row i (parallel)
__global__ __launch_bounds__(256) void cursor_kernel(
    const int* __restrict__ row_off, const int* __restrict__ deg2,
    int* __restrict__ cursor2, int N, int nchunk)
{
    int i = blockIdx.x * 256 + threadIdx.x;
    if (i < N) {
        int p = row_off[i];
        for (int c = 0; c < nchunk; ++c) {
            cursor2[(size_t)i * nchunk + c] = p;
            p += deg2[(size_t)i * nchunk + c];
        }
    }
}

// single pass: edges land grouped by (dst row, src chunk)
__global__ __launch_bounds__(256) void scatter_kernel(
    const int* __restrict__ src, const int* __restrict__ dst,
    const float* __restrict__ ew, int* __restrict__ cursor2,
    int2* __restrict__ edge_s, int E, int nchunk)
{
    int e = blockIdx.x * 256 + threadIdx.x;
    if (e < E) {
        int s = src[e];
        int pos = atomicAdd(&cursor2[(size_t)dst[e] * nchunk + (s >> CSH)], 1);
        edge_s[pos] = make_int2(s, __float_as_int(ew[e]));
    }
}

// sdeg[i] = sum of ew over row i
__global__ __launch_bounds__(256) void sdeg_kernel(
    const int* __restrict__ row_off, const int2* __restrict__ edge_s,
    float* __restrict__ sdeg, int N)
{
    int lane = threadIdx.x & 63;
    int node = blockIdx.x * 4 + (threadIdx.x >> 6);
    if (node >= N) return;
    int beg = row_off[node], end = row_off[node + 1];
    float s = 0.f;
    for (int e = beg + lane; e < end; e += 64)
        s += __int_as_float(edge_s[e].y);
    #pragma unroll
    for (int off = 32; off; off >>= 1) s += __shfl_xor(s, off);
    if (lane == 0) sdeg[node] = s;
}

// ---------------- fused 3-matmul per layer (single k-sweep) ----------------
// aA/aB[n] = halves of (W1 h[n] + b1);  base = (W3 h + b3) - s*(W2 h)
// 256 threads, 32 nodes/block. tn=tid&7 (4 nodes), to=tid>>3 (4 outs).
// Per thread: acc[3][4][4]. Per 4-k chunk: 192 FMA vs 4 LDS b128 + 12 W
// float4 (ping-pong double-buffered a full chunk ahead).

__global__ __launch_bounds__(256, 2) void gemm_kernel(
    const float* __restrict__ in, const float* __restrict__ W1,
    const float* __restrict__ b1, const float* __restrict__ W2,
    const float* __restrict__ W3, const float* __restrict__ b3,
    const float* __restrict__ sdeg, float* __restrict__ aA,
    float* __restrict__ aB, float* __restrict__ base_out, int N)
{
    __shared__ float Hs[128][36];   // [k][node], padded

    int tid = threadIdx.x;
    int tn  = tid & 7;         // 8 node-threads x 4 nodes = 32
    int to  = tid >> 3;        // 32 out-threads x 4 outs = 128
    int n0  = blockIdx.x * 32;
    int o0  = to * 4;

    // stage H transposed; r-inner order => conflict-free LDS writes
    for (int idx = tid; idx < 1024; idx += 256) {
        int r  = idx & 31;
        int c4 = idx >> 5;
        float4 v = make_float4(0.f, 0.f, 0.f, 0.f);
        if (n0 + r < N)
            v = *(const float4*)&in[(size_t)(n0 + r) * D + c4 * 4];
        Hs[c4 * 4 + 0][r] = v.x;
        Hs[c4 * 4 + 1][r] = v.y;
        Hs[c4 * 4 + 2][r] = v.z;
        Hs[c4 * 4 + 3][r] = v.w;
    }
    __syncthreads();           // ONLY barrier

    const float* Wm[3] = {W1, W2, W3};

    auto loadW = [&](int kc, float4 (&w)[3][4]) {
        #pragma unroll
        for (int m = 0; m < 3; ++m)
            #pragma unroll
            for (int j = 0; j < 4; ++j)
                w[m][j] = *(const float4*)&Wm[m][(size_t)(o0 + j) * D + kc];
    };

    float acc[3][4][4];
    #pragma unroll
    for (int m = 0; m < 3; ++m)
        #pragma unroll
        for (int i = 0; i < 4; ++i)
            #pragma unroll
            for (int j = 0; j < 4; ++j) acc[m][i][j] = 0.f;

    auto fmas = [&](int kc, const float4 (&w)[3][4]) {
        float4 hv[4];
        #pragma unroll
        for (int kk = 0; kk < 4; ++kk)
            hv[kk] = *(const float4*)&Hs[kc + kk][tn * 4];
        #pragma unroll
        for (int kk = 0; kk < 4; ++kk) {
            float hh[4] = {hv[kk].x, hv[kk].y, hv[kk].z, hv[kk].w};
            #pragma unroll
            for (int m = 0; m < 3; ++m)
                #pragma unroll
                for (int j = 0; j < 4; ++j) {
                    float wf = ((const float*)&w[m][j])[kk];
                    #pragma unroll
                    for (int i = 0; i < 4; ++i)
                        acc[m][i][j] = fmaf(hh[i], wf, acc[m][i][j]);
                }
        }
    };

    float4 wA[3][4], wB[3][4];
    loadW(0, wA);
    for (int kc = 0; kc < D; kc += 8) {
        loadW(kc + 4, wB);
        fmas(kc, wA);
        if (kc + 8 < D) loadW(kc + 8, wA);
        fmas(kc + 4, wB);
    }

    // ---- epilogue ----
    float4 b1v = *(const float4*)&b1[o0];
    float4 b3v = *(const float4*)&b3[o0];
    float bf1[4] = {b1v.x, b1v.y, b1v.z, b1v.w};
    float bf3[4] = {b3v.x, b3v.y, b3v.z, b3v.w};
    float* ah = (o0 < 64) ? aA : aB;
    int    oh = o0 & 63;

    #pragma unroll
    for (int i = 0; i < 4; ++i) {
        int row = n0 + tn * 4 + i;
        if (row < N) {
            float sv = sdeg[row];
            float4 av = make_float4(acc[0][i][0] + bf1[0], acc[0][i][1] + bf1[1],
                                    acc[0][i][2] + bf1[2], acc[0][i][3] + bf1[3]);
            float4 bv = make_float4(acc[2][i][0] + bf3[0] - sv * acc[1][i][0],
                                    acc[2][i][1] + bf3[1] - sv * acc[1][i][1],
                                    acc[2][i][2] + bf3[2] - sv * acc[1][i][2],
                                    acc[2][i][3] + bf3[3] - sv * acc[1][i][3]);
            *(float4*)&ah[(size_t)row * 64 + oh]      = av;
            *(float4*)&base_out[(size_t)row * D + o0] = bv;
        }
    }
}

// ---------------- CSR aggregate + activation (one 64-feature half) ------

__global__ __launch_bounds__(256) void agg_kernel(
    const float* __restrict__ aH, const float* __restrict__ base,
    const int* __restrict__ row_off, const int2* __restrict__ edge_s,
    float* __restrict__ out, int N, int hofs, int last)
{
    int lane = threadIdx.x & 63;
    int node = blockIdx.x * 4 + (threadIdx.x >> 6);
    if (node >= N) return;

    float acc = base[(size_t)node * D + hofs + lane];
    int beg = row_off[node];
    int end = row_off[node + 1];

    int e = beg;
    if ((e & 1) && e < end) {         // peel to align int4 batches
        int2 ed = edge_s[e];
        acc = fmaf(__int_as_float(ed.y), aH[(size_t)ed.x * 64 + lane], acc);
        ++e;
    }
    for (; e + 16 <= end; e += 16) {  // 16 edges, 8 aligned int4 loads
        int4 ed[8];
        #pragma unroll
        for (int i = 0; i < 8; ++i) ed[i] = *(const int4*)&edge_s[e + i * 2];
        float v[16];
        #pragma unroll
        for (int i = 0; i < 8; ++i) {
            v[2 * i]     = aH[(size_t)ed[i].x * 64 + lane];
            v[2 * i + 1] = aH[(size_t)ed[i].z * 64 + lane];
        }
        #pragma unroll
        for (int i = 0; i < 8; ++i) {
            acc = fmaf(__int_as_float(ed[i].y), v[2 * i], acc);
            acc = fmaf(__int_as_float(ed[i].w), v[2 * i + 1], acc);
        }
    }
    for (; e + 4 <= end; e += 4) {
        int4 e0 = *(const int4*)&edge_s[e];
        int4 e1 = *(const int4*)&edge_s[e + 2];
        float v0 = aH[(size_t)e0.x * 64 + lane];
        float v1 = aH[(size_t)e0.z * 64 + lane];
        float v2 = aH[(size_t)e1.x * 64 + lane];
        float v3 = aH[(size_t)e1.z * 64 + lane];
        acc = fmaf(__int_as_float(e0.y), v0, acc);
        acc = fmaf(__int_as_float(e0.w), v1, acc);
        acc = fmaf(__int_as_float(e1.y), v2, acc);
        acc = fmaf(__int_as_float(e1.w), v3, acc);
    }
    for (; e < end; ++e) {
        int2 ed = edge_s[e];
        acc = fmaf(__int_as_float(ed.y), aH[(size_t)ed.x * 64 + lane], acc);
    }

    acc = acc >= 0.f ? acc : 0.1f * acc;          // leaky relu 0.1
    if (last) acc = 1.f / (1.f + __expf(-acc));   // sigmoid
    out[(size_t)node * D + hofs + lane] = acc;
}

// ---------------- launch ----------------

extern "C" void kernel_launch(void* const* d_in, const int* in_sizes, int n_in,
                              void* d_out, int out_size, void* d_ws, size_t ws_size,
                              hipStream_t stream) {
    const float* x   = (const float*)d_in[0];
    const int*   ei  = (const int*)d_in[1];
    const float* ew  = (const float*)d_in[2];
    const float* iW1 = (const float*)d_in[3];
    const float* ib1 = (const float*)d_in[4];
    const float* iW2 = (const float*)d_in[5];
    const float* iW3 = (const float*)d_in[6];
    const float* ib3 = (const float*)d_in[7];
    const float* mW1 = (const float*)d_in[8];
    const float* mb1 = (const float*)d_in[9];
    const float* mW2 = (const float*)d_in[10];
    const float* mW3 = (const float*)d_in[11];
    const float* mb3 = (const float*)d_in[12];
    const float* oW1 = (const float*)d_in[13];
    const float* ob1 = (const float*)d_in[14];
    const float* oW2 = (const float*)d_in[15];
    const float* oW3 = (const float*)d_in[16];
    const float* ob3 = (const float*)d_in[17];

    int N = in_sizes[0] / D;
    int E = in_sizes[2];
    const int* src = ei;
    const int* dst = ei + E;
    int nchunk = (N + (1 << CSH) - 1) >> CSH;

    char* wsp = (char*)d_ws;
    size_t off = 0;
    auto alloc = [&](size_t bytes) -> void* {
        void* p = wsp + off;
        off += (bytes + 255) & ~(size_t)255;
        return p;
    };
    float* h       = (float*)alloc((size_t)N * D * 4);
    float* base    = (float*)alloc((size_t)N * D * 4);
    float* aA      = (float*)alloc((size_t)N * 64 * 4);
    float* aB      = (float*)alloc((size_t)N * 64 * 4);
    float* sdeg    = (float*)alloc((size_t)N * 4);
    int*   deg     = (int*)alloc((size_t)N * 4);
    int*   deg2    = (int*)alloc((size_t)N * nchunk * 4);
    int*   cursor2 = (int*)alloc((size_t)N * nchunk * 4);
    int*   row_off = (int*)alloc((size_t)(N + 1) * 4);
    int2*  edge_s  = (int2*)alloc((size_t)E * 8);

    hipMemsetAsync(deg2, 0, (size_t)N * nchunk * 4, stream);

    int eblocks = (E + 255) / 256;
    int nblocks = (N + 255) / 256;
    int ablocks = (N + 3) / 4;
    int gblocks = (N + 31) / 32;

    count_kernel<<<eblocks, 256, 0, stream>>>(src, dst, deg2, E, nchunk);
    rowsum_kernel<<<nblocks, 256, 0, stream>>>(deg2, deg, N, nchunk);
    scan_kernel<<<1, 1024, 0, stream>>>(deg, row_off, N);
    cursor_kernel<<<nblocks, 256, 0, stream>>>(row_off, deg2, cursor2, N, nchunk);
    scatter_kernel<<<eblocks, 256, 0, stream>>>(src, dst, ew, cursor2, edge_s, E, nchunk);
    sdeg_kernel<<<ablocks, 256, 0, stream>>>(row_off, edge_s, sdeg, N);

    // layer 1 (in): reads x
    gemm_kernel<<<gblocks, 256, 0, stream>>>(x, iW1, ib1, iW2, iW3, ib3, sdeg, aA, aB, base, N);
    agg_kernel<<<ablocks, 256, 0, stream>>>(aA, base, row_off, edge_s, h, N, 0, 0);
    agg_kernel<<<ablocks, 256, 0, stream>>>(aB, base, row_off, edge_s, h, N, 64, 0);
    // layers 2..3 (mid, shared weights)
    for (int l = 0; l < 2; ++l) {
        gemm_kernel<<<gblocks, 256, 0, stream>>>(h, mW1, mb1, mW2, mW3, mb3, sdeg, aA, aB, base, N);
        agg_kernel<<<ablocks, 256, 0, stream>>>(aA, base, row_off, edge_s, h, N, 0, 0);
        agg_kernel<<<ablocks, 256, 0, stream>>>(aB, base, row_off, edge_s, h, N, 64, 0);
    }
    // layer 4 (out) -> d_out with sigmoid
    gemm_kernel<<<gblocks, 256, 0, stream>>>(h, oW1, ob1, oW2, oW3, ob3, sdeg, aA, aB, base, N);
    agg_kernel<<<ablocks, 256, 0, stream>>>(aA, base, row_off, edge_s, (float*)d_out, N, 0, 1);
    agg_kernel<<<ablocks, 256, 0, stream>>>(aB, base, row_off, edge_s, (float*)d_out, N, 64, 1);
}

// Round 8
// 864.722 us; speedup vs baseline: 1.3975x; 1.2151x over previous
//
#include <hip/hip_runtime.h>
#include <hip/hip_fp16.h>
#include <math.h>

#define D 128
#define CSH 13   // src-chunk shift: 8192 nodes/chunk -> 7 chunks at N=50000

typedef _Float16 f16;
typedef __attribute__((ext_vector_type(8))) _Float16 f16x8;
typedef __attribute__((ext_vector_type(4))) float f32x4;

// ---------------- preprocessing (unchanged from round 7) ----------------

__global__ __launch_bounds__(256) void count_kernel(
    const int* __restrict__ src, const int* __restrict__ dst,
    int* __restrict__ deg2, int E, int nchunk)
{
    int e = blockIdx.x * 256 + threadIdx.x;
    if (e < E) {
        int c = src[e] >> CSH;
        atomicAdd(&deg2[(size_t)dst[e] * nchunk + c], 1);
    }
}

__global__ __launch_bounds__(256) void rowsum_kernel(
    const int* __restrict__ deg2, int* __restrict__ deg, int N, int nchunk)
{
    int i = blockIdx.x * 256 + threadIdx.x;
    if (i < N) {
        int s = 0;
        for (int c = 0; c < nchunk; ++c) s += deg2[(size_t)i * nchunk + c];
        deg[i] = s;
    }
}

__global__ __launch_bounds__(1024) void scan_kernel(
    const int* __restrict__ deg, int* __restrict__ row_off, int n)
{
    __shared__ int wsum[16];
    int tid  = threadIdx.x;
    int lane = tid & 63;
    int wid  = tid >> 6;
    int carry = 0;
    for (int base = 0; base < n; base += 1024) {
        int i = base + tid;
        int v = (i < n) ? deg[i] : 0;
        int x = v;
        #pragma unroll
        for (int off = 1; off < 64; off <<= 1) {
            int t = __shfl_up(x, off);
            if (lane >= off) x += t;
        }
        __syncthreads();
        if (lane == 63) wsum[wid] = x;
        __syncthreads();
        if (tid < 16) {
            int y = wsum[tid];
            #pragma unroll
            for (int off = 1; off < 16; off <<= 1) {
                int t = __shfl_up(y, off, 16);
                if (tid >= off) y += t;
            }
            wsum[tid] = y;
        }
        __syncthreads();
        int wexcl = wid ? wsum[wid - 1] : 0;
        int excl  = carry + wexcl + x - v;
        if (i < n) row_off[i] = excl;
        carry += wsum[15];
    }
    if (tid == 0) row_off[n] = carry;
}

__global__ __launch_bounds__(256) void cursor_kernel(
    const int* __restrict__ row_off, const int* __restrict__ deg2,
    int* __restrict__ cursor2, int N, int nchunk)
{
    int i = blockIdx.x * 256 + threadIdx.x;
    if (i < N) {
        int p = row_off[i];
        for (int c = 0; c < nchunk; ++c) {
            cursor2[(size_t)i * nchunk + c] = p;
            p += deg2[(size_t)i * nchunk + c];
        }
    }
}

__global__ __launch_bounds__(256) void scatter_kernel(
    const int* __restrict__ src, const int* __restrict__ dst,
    const float* __restrict__ ew, int* __restrict__ cursor2,
    int2* __restrict__ edge_s, int E, int nchunk)
{
    int e = blockIdx.x * 256 + threadIdx.x;
    if (e < E) {
        int s = src[e];
        int pos = atomicAdd(&cursor2[(size_t)dst[e] * nchunk + (s >> CSH)], 1);
        edge_s[pos] = make_int2(s, __float_as_int(ew[e]));
    }
}

__global__ __launch_bounds__(256) void sdeg_kernel(
    const int* __restrict__ row_off, const int2* __restrict__ edge_s,
    float* __restrict__ sdeg, int N)
{
    int lane = threadIdx.x & 63;
    int node = blockIdx.x * 4 + (threadIdx.x >> 6);
    if (node >= N) return;
    int beg = row_off[node], end = row_off[node + 1];
    float s = 0.f;
    for (int e = beg + lane; e < end; e += 64)
        s += __int_as_float(edge_s[e].y);
    #pragma unroll
    for (int off = 32; off; off >>= 1) s += __shfl_xor(s, off);
    if (lane == 0) sdeg[node] = s;
}

// ---------------- W pack: f32 -> fp16 hi/lo in MFMA B-fragment order -----
// Layout (halves): Wp[ks*24576 + mot*1024 + h*512 + lane*8 + j]
//   mot = m*8+ot (m in {W1,W2,W3}, ot = 16-out tile), ks = 32-k step,
//   h = 0:hi 1:lo. B-frag convention: col = lane&15, k = ks*32+(lane>>4)*8+j.
__global__ __launch_bounds__(256) void pack_kernel(
    const float* __restrict__ W1, const float* __restrict__ W2,
    const float* __restrict__ W3, f16* __restrict__ Wp)
{
    int idx = blockIdx.x * 256 + threadIdx.x;   // 6144 total
    if (idx >= 6144) return;
    int lane = idx & 63;
    int t    = idx >> 6;       // 0..95
    int ks   = t & 3;
    int mot  = t >> 2;         // 0..23
    int m    = mot >> 3;
    int ot   = mot & 7;
    const float* W = (m == 0) ? W1 : (m == 1) ? W2 : W3;
    int o  = ot * 16 + (lane & 15);
    int kb = ks * 32 + (lane >> 4) * 8;
    f16x8 hi, lo;
    #pragma unroll
    for (int j = 0; j < 8; ++j) {
        float v = W[(size_t)o * D + kb + j];
        f16 hh = (f16)v;
        hi[j] = hh;
        lo[j] = (f16)(v - (float)hh);
    }
    size_t base = (size_t)ks * 24576 + (size_t)mot * 1024 + (size_t)lane * 8;
    *(f16x8*)&Wp[base]       = hi;
    *(f16x8*)&Wp[base + 512] = lo;
}

// ---------------- MFMA fused 3-matmul per layer --------------------------
// Split-fp16 f32 emulation: x = hi + lo; h.W ~= hi.Whi + lo.Whi + hi.Wlo.
// 256 threads = 4 waves; each wave owns a 16-node tile x all 128 outs x 3 W.
// Per ks: stage 48KB Wp slice -> LDS (shared by 4 waves), A-frag from global.
// acc[24] f32x4 (mot-indexed, fully unrolled => registers).
// D layout (HW-verified): col = lane&15 (out), row = (lane>>4)*4 + reg (node).

__global__ __launch_bounds__(256, 3) void gemm_kernel(
    const float* __restrict__ in, const f16* __restrict__ Wp,
    const float* __restrict__ b1, const float* __restrict__ b3,
    const float* __restrict__ sdeg, float* __restrict__ aA,
    float* __restrict__ aB, float* __restrict__ base_out, int N)
{
    __shared__ f16 Blds[24576];   // 48KB: [mot][h][lane*8]

    int tid  = threadIdx.x;
    int lane = tid & 63;
    int wid  = tid >> 6;
    int n0   = (blockIdx.x * 4 + wid) * 16;
    int col  = lane & 15;
    int g    = lane >> 4;
    int nrow = n0 + col;           // A-row node for this lane

    f32x4 acc[24];
    #pragma unroll
    for (int i = 0; i < 24; ++i) acc[i] = (f32x4){0.f, 0.f, 0.f, 0.f};

    for (int ks = 0; ks < 4; ++ks) {
        // A fragment: lane holds h[nrow][ks*32 + g*8 + j], j=0..7
        float av[8];
        if (nrow < N) {
            float4 a0 = *(const float4*)&in[(size_t)nrow * D + ks * 32 + g * 8];
            float4 a1 = *(const float4*)&in[(size_t)nrow * D + ks * 32 + g * 8 + 4];
            av[0] = a0.x; av[1] = a0.y; av[2] = a0.z; av[3] = a0.w;
            av[4] = a1.x; av[5] = a1.y; av[6] = a1.z; av[7] = a1.w;
        } else {
            #pragma unroll
            for (int j = 0; j < 8; ++j) av[j] = 0.f;
        }
        f16x8 ahi, alo;
        #pragma unroll
        for (int j = 0; j < 8; ++j) {
            f16 hh = (f16)av[j];
            ahi[j] = hh;
            alo[j] = (f16)(av[j] - (float)hh);
        }

        __syncthreads();           // previous ks compute done before overwrite
        {
            const f16x8* s4 = (const f16x8*)(Wp + (size_t)ks * 24576);
            f16x8* d4 = (f16x8*)Blds;
            for (int i = tid; i < 3072; i += 256) d4[i] = s4[i];
        }
        __syncthreads();

        #pragma unroll
        for (int mot = 0; mot < 24; ++mot) {
            f16x8 bhi = *(const f16x8*)&Blds[mot * 1024 + lane * 8];
            f16x8 blo = *(const f16x8*)&Blds[mot * 1024 + 512 + lane * 8];
            acc[mot] = __builtin_amdgcn_mfma_f32_16x16x32_f16(ahi, bhi, acc[mot], 0, 0, 0);
            acc[mot] = __builtin_amdgcn_mfma_f32_16x16x32_f16(alo, bhi, acc[mot], 0, 0, 0);
            acc[mot] = __builtin_amdgcn_mfma_f32_16x16x32_f16(ahi, blo, acc[mot], 0, 0, 0);
        }
    }

    // epilogue
    #pragma unroll
    for (int ot = 0; ot < 8; ++ot) {
        int o = ot * 16 + col;
        float bi1 = b1[o];
        float bi3 = b3[o];
        float* ah = (o < 64) ? aA : aB;
        int    oh = o & 63;
        #pragma unroll
        for (int r = 0; r < 4; ++r) {
            int node = n0 + g * 4 + r;
            if (node < N) {
                float sv   = sdeg[node];
                float aval = acc[ot][r] + bi1;
                float bval = acc[16 + ot][r] + bi3 - sv * acc[8 + ot][r];
                ah[(size_t)node * 64 + oh]     = aval;
                base_out[(size_t)node * D + o] = bval;
            }
        }
    }
}

// ---------------- CSR aggregate + activation (one 64-feature half) ------

__global__ __launch_bounds__(256) void agg_kernel(
    const float* __restrict__ aH, const float* __restrict__ base,
    const int* __restrict__ row_off, const int2* __restrict__ edge_s,
    float* __restrict__ out, int N, int hofs, int last)
{
    int lane = threadIdx.x & 63;
    int node = blockIdx.x * 4 + (threadIdx.x >> 6);
    if (node >= N) return;

    float acc = base[(size_t)node * D + hofs + lane];
    int beg = row_off[node];
    int end = row_off[node + 1];

    int e = beg;
    if ((e & 1) && e < end) {         // peel to align int4 batches
        int2 ed = edge_s[e];
        acc = fmaf(__int_as_float(ed.y), aH[(size_t)ed.x * 64 + lane], acc);
        ++e;
    }
    for (; e + 16 <= end; e += 16) {  // 16 edges, 8 aligned int4 loads
        int4 ed[8];
        #pragma unroll
        for (int i = 0; i < 8; ++i) ed[i] = *(const int4*)&edge_s[e + i * 2];
        float v[16];
        #pragma unroll
        for (int i = 0; i < 8; ++i) {
            v[2 * i]     = aH[(size_t)ed[i].x * 64 + lane];
            v[2 * i + 1] = aH[(size_t)ed[i].z * 64 + lane];
        }
        #pragma unroll
        for (int i = 0; i < 8; ++i) {
            acc = fmaf(__int_as_float(ed[i].y), v[2 * i], acc);
            acc = fmaf(__int_as_float(ed[i].w), v[2 * i + 1], acc);
        }
    }
    for (; e + 4 <= end; e += 4) {
        int4 e0 = *(const int4*)&edge_s[e];
        int4 e1 = *(const int4*)&edge_s[e + 2];
        float v0 = aH[(size_t)e0.x * 64 + lane];
        float v1 = aH[(size_t)e0.z * 64 + lane];
        float v2 = aH[(size_t)e1.x * 64 + lane];
        float v3 = aH[(size_t)e1.z * 64 + lane];
        acc = fmaf(__int_as_float(e0.y), v0, acc);
        acc = fmaf(__int_as_float(e0.w), v1, acc);
        acc = fmaf(__int_as_float(e1.y), v2, acc);
        acc = fmaf(__int_as_float(e1.w), v3, acc);
    }
    for (; e < end; ++e) {
        int2 ed = edge_s[e];
        acc = fmaf(__int_as_float(ed.y), aH[(size_t)ed.x * 64 + lane], acc);
    }

    acc = acc >= 0.f ? acc : 0.1f * acc;          // leaky relu 0.1
    if (last) acc = 1.f / (1.f + __expf(-acc));   // sigmoid
    out[(size_t)node * D + hofs + lane] = acc;
}

// ---------------- launch ----------------

extern "C" void kernel_launch(void* const* d_in, const int* in_sizes, int n_in,
                              void* d_out, int out_size, void* d_ws, size_t ws_size,
                              hipStream_t stream) {
    const float* x   = (const float*)d_in[0];
    const int*   ei  = (const int*)d_in[1];
    const float* ew  = (const float*)d_in[2];
    const float* iW1 = (const float*)d_in[3];
    const float* ib1 = (const float*)d_in[4];
    const float* iW2 = (const float*)d_in[5];
    const float* iW3 = (const float*)d_in[6];
    const float* ib3 = (const float*)d_in[7];
    const float* mW1 = (const float*)d_in[8];
    const float* mb1 = (const float*)d_in[9];
    const float* mW2 = (const float*)d_in[10];
    const float* mW3 = (const float*)d_in[11];
    const float* mb3 = (const float*)d_in[12];
    const float* oW1 = (const float*)d_in[13];
    const float* ob1 = (const float*)d_in[14];
    const float* oW2 = (const float*)d_in[15];
    const float* oW3 = (const float*)d_in[16];
    const float* ob3 = (const float*)d_in[17];

    int N = in_sizes[0] / D;
    int E = in_sizes[2];
    const int* src = ei;
    const int* dst = ei + E;
    int nchunk = (N + (1 << CSH) - 1) >> CSH;

    char* wsp = (char*)d_ws;
    size_t off = 0;
    auto alloc = [&](size_t bytes) -> void* {
        void* p = wsp + off;
        off += (bytes + 255) & ~(size_t)255;
        return p;
    };
    float* h       = (float*)alloc((size_t)N * D * 4);
    float* base    = (float*)alloc((size_t)N * D * 4);
    float* aA      = (float*)alloc((size_t)N * 64 * 4);
    float* aB      = (float*)alloc((size_t)N * 64 * 4);
    float* sdeg    = (float*)alloc((size_t)N * 4);
    int*   deg     = (int*)alloc((size_t)N * 4);
    int*   deg2    = (int*)alloc((size_t)N * nchunk * 4);
    int*   cursor2 = (int*)alloc((size_t)N * nchunk * 4);
    int*   row_off = (int*)alloc((size_t)(N + 1) * 4);
    int2*  edge_s  = (int2*)alloc((size_t)E * 8);
    f16*   Wp      = (f16*)alloc((size_t)3 * 98304 * 2);   // 3 sets x 96K halves

    hipMemsetAsync(deg2, 0, (size_t)N * nchunk * 4, stream);

    int eblocks = (E + 255) / 256;
    int nblocks = (N + 255) / 256;
    int ablocks = (N + 3) / 4;
    int tiles   = (N + 15) / 16;
    int gblocks = (tiles + 3) / 4;

    // pack all three layer-sets (independent of graph preprocessing)
    pack_kernel<<<24, 256, 0, stream>>>(iW1, iW2, iW3, Wp);
    pack_kernel<<<24, 256, 0, stream>>>(mW1, mW2, mW3, Wp + 98304);
    pack_kernel<<<24, 256, 0, stream>>>(oW1, oW2, oW3, Wp + 2 * 98304);

    count_kernel<<<eblocks, 256, 0, stream>>>(src, dst, deg2, E, nchunk);
    rowsum_kernel<<<nblocks, 256, 0, stream>>>(deg2, deg, N, nchunk);
    scan_kernel<<<1, 1024, 0, stream>>>(deg, row_off, N);
    cursor_kernel<<<nblocks, 256, 0, stream>>>(row_off, deg2, cursor2, N, nchunk);
    scatter_kernel<<<eblocks, 256, 0, stream>>>(src, dst, ew, cursor2, edge_s, E, nchunk);
    sdeg_kernel<<<ablocks, 256, 0, stream>>>(row_off, edge_s, sdeg, N);

    // layer 1 (in): reads x
    gemm_kernel<<<gblocks, 256, 0, stream>>>(x, Wp, ib1, ib3, sdeg, aA, aB, base, N);
    agg_kernel<<<ablocks, 256, 0, stream>>>(aA, base, row_off, edge_s, h, N, 0, 0);
    agg_kernel<<<ablocks, 256, 0, stream>>>(aB, base, row_off, edge_s, h, N, 64, 0);
    // layers 2..3 (mid, shared weights)
    for (int l = 0; l < 2; ++l) {
        gemm_kernel<<<gblocks, 256, 0, stream>>>(h, Wp + 98304, mb1, mb3, sdeg, aA, aB, base, N);
        agg_kernel<<<ablocks, 256, 0, stream>>>(aA, base, row_off, edge_s, h, N, 0, 0);
        agg_kernel<<<ablocks, 256, 0, stream>>>(aB, base, row_off, edge_s, h, N, 64, 0);
    }
    // layer 4 (out) -> d_out with sigmoid
    gemm_kernel<<<gblocks, 256, 0, stream>>>(h, Wp + 2 * 98304, ob1, ob3, sdeg, aA, aB, base, N);
    agg_kernel<<<ablocks, 256, 0, stream>>>(aA, base, row_off, edge_s, (float*)d_out, N, 0, 1);
    agg_kernel<<<ablocks, 256, 0, stream>>>(aB, base, row_off, edge_s, (float*)d_out, N, 64, 1);
}

// Round 9
// 727.311 us; speedup vs baseline: 1.6615x; 1.1889x over previous
//
#include <hip/hip_runtime.h>
#include <hip/hip_fp16.h>
#include <math.h>

#define D 128
#define CSH 13      // src-chunk shift: 8192 nodes/chunk -> 7 chunks at N=50000
#define BSH 9       // dst-bucket shift: 512 nodes/bucket -> 98 buckets
#define NB_MAX 128

typedef _Float16 f16;
typedef __attribute__((ext_vector_type(8))) _Float16 f16x8;
typedef __attribute__((ext_vector_type(4))) float f32x4;

// ---------------- preprocessing: two-level binning ----------------

// Pass A1: coarse histogram (LDS-staged; 98 global atomics per block)
__global__ __launch_bounds__(256) void binA_count(
    const int* __restrict__ dst, int* __restrict__ bucketCount, int E)
{
    __shared__ int hist[NB_MAX];
    int tid = threadIdx.x;
    if (tid < NB_MAX) hist[tid] = 0;
    __syncthreads();
    int base = blockIdx.x * 4096;
    for (int i = tid; i < 4096; i += 256) {
        int e = base + i;
        if (e < E) atomicAdd(&hist[dst[e] >> BSH], 1);
    }
    __syncthreads();
    if (tid < NB_MAX && hist[tid]) atomicAdd(&bucketCount[tid], hist[tid]);
}

// tiny serial scan over <=128 buckets; also seeds row_off[N]
__global__ void bucket_scan(
    const int* __restrict__ bucketCount, int* __restrict__ bucketBase,
    int* __restrict__ bucketCursor, int* __restrict__ row_off,
    int NBUC, int E, int N)
{
    if (threadIdx.x == 0 && blockIdx.x == 0) {
        int p = 0;
        for (int b = 0; b < NBUC; ++b) {
            bucketBase[b] = p; bucketCursor[b] = p; p += bucketCount[b];
        }
        bucketBase[NBUC] = p;
        row_off[N] = E;
    }
}

// Pass A2: scatter into bucket-contiguous chunks (block-reserved)
__global__ __launch_bounds__(256) void binA_scatter(
    const int* __restrict__ src, const int* __restrict__ dst,
    const float* __restrict__ ew, int* __restrict__ bucketCursor,
    int4* __restrict__ binned, int E)
{
    __shared__ int hist[NB_MAX], off[NB_MAX], cbase[NB_MAX];
    int tid = threadIdx.x;
    if (tid < NB_MAX) { hist[tid] = 0; off[tid] = 0; }
    __syncthreads();
    int base = blockIdx.x * 4096;
    for (int i = tid; i < 4096; i += 256) {
        int e = base + i;
        if (e < E) atomicAdd(&hist[dst[e] >> BSH], 1);
    }
    __syncthreads();
    if (tid < NB_MAX && hist[tid])
        cbase[tid] = atomicAdd(&bucketCursor[tid], hist[tid]);
    __syncthreads();
    for (int i = tid; i < 4096; i += 256) {
        int e = base + i;
        if (e < E) {
            int d = dst[e];
            int b = d >> BSH;
            int pos = cbase[b] + atomicAdd(&off[b], 1);
            binned[pos] = make_int4(src[e], __float_as_int(ew[e]), d, 0);
        }
    }
}

// Pass B: exact CSR per bucket, all atomics in LDS; writes stay in a
// ~130KB contiguous window (L2-assembled). Emits row_off, edge_s, sdeg.
__global__ __launch_bounds__(1024) void binB_kernel(
    const int4* __restrict__ binned, const int* __restrict__ bucketBase,
    int2* __restrict__ edge_s, int* __restrict__ row_off,
    float* __restrict__ sdeg, int N, int nchunk)
{
    __shared__ int hist[4096];
    __shared__ int cur[4096];
    __shared__ float sdl[512];
    __shared__ int wsum[16];

    int b    = blockIdx.x;
    int tid  = threadIdx.x;
    int ebeg = bucketBase[b], eend = bucketBase[b + 1];
    int node0 = b << BSH;
    int nib   = min(512, N - node0);

    for (int i = tid; i < 4096; i += 1024) hist[i] = 0;
    for (int i = tid; i < 512; i += 1024) sdl[i] = 0.f;
    __syncthreads();

    for (int e = ebeg + tid; e < eend; e += 1024) {
        int4 ed = binned[e];
        int dl = ed.z - node0;
        int ch = ((unsigned)ed.x) >> CSH;
        atomicAdd(&hist[dl * nchunk + ch], 1);
        atomicAdd(&sdl[dl], __int_as_float(ed.y));
    }
    __syncthreads();

    // block exclusive scan hist[0..4095] -> cur (unused tail keys are 0)
    int t4 = tid * 4;
    int h0 = hist[t4], h1 = hist[t4 + 1], h2 = hist[t4 + 2], h3 = hist[t4 + 3];
    int sum = h0 + h1 + h2 + h3;
    int lane = tid & 63, wid = tid >> 6;
    int x = sum;
    #pragma unroll
    for (int o = 1; o < 64; o <<= 1) { int t = __shfl_up(x, o); if (lane >= o) x += t; }
    if (lane == 63) wsum[wid] = x;
    __syncthreads();
    if (tid < 16) {
        int y = wsum[tid];
        #pragma unroll
        for (int o = 1; o < 16; o <<= 1) { int t = __shfl_up(y, o, 16); if (tid >= o) y += t; }
        wsum[tid] = y;
    }
    __syncthreads();
    int excl = (wid ? wsum[wid - 1] : 0) + x - sum;
    cur[t4] = excl; cur[t4 + 1] = excl + h0;
    cur[t4 + 2] = excl + h0 + h1; cur[t4 + 3] = excl + h0 + h1 + h2;
    __syncthreads();

    // row_off + sdeg (before cur is mutated by the scatter)
    for (int dl = tid; dl < nib; dl += 1024) {
        row_off[node0 + dl] = ebeg + cur[dl * nchunk];
        sdeg[node0 + dl]    = sdl[dl];
    }
    __syncthreads();

    for (int e = ebeg + tid; e < eend; e += 1024) {
        int4 ed = binned[e];
        int dl = ed.z - node0;
        int ch = ((unsigned)ed.x) >> CSH;
        int pos = ebeg + atomicAdd(&cur[dl * nchunk + ch], 1);
        edge_s[pos] = make_int2(ed.x, ed.y);
    }
}

// ---------------- W pack: f32 -> fp16 hi/lo in MFMA B-fragment order -----
__global__ __launch_bounds__(256) void pack_kernel(
    const float* __restrict__ W1, const float* __restrict__ W2,
    const float* __restrict__ W3, f16* __restrict__ Wp)
{
    int idx = blockIdx.x * 256 + threadIdx.x;   // 6144 total
    if (idx >= 6144) return;
    int lane = idx & 63;
    int t    = idx >> 6;       // 0..95
    int ks   = t & 3;
    int mot  = t >> 2;         // 0..23
    int m    = mot >> 3;
    int ot   = mot & 7;
    const float* W = (m == 0) ? W1 : (m == 1) ? W2 : W3;
    int o  = ot * 16 + (lane & 15);
    int kb = ks * 32 + (lane >> 4) * 8;
    f16x8 hi, lo;
    #pragma unroll
    for (int j = 0; j < 8; ++j) {
        float v = W[(size_t)o * D + kb + j];
        f16 hh = (f16)v;
        hi[j] = hh;
        lo[j] = (f16)(v - (float)hh);
    }
    size_t base = (size_t)ks * 24576 + (size_t)mot * 1024 + (size_t)lane * 8;
    *(f16x8*)&Wp[base]       = hi;
    *(f16x8*)&Wp[base + 512] = lo;
}

// ---------------- MFMA fused 3-matmul per layer --------------------------
__global__ __launch_bounds__(256, 3) void gemm_kernel(
    const float* __restrict__ in, const f16* __restrict__ Wp,
    const float* __restrict__ b1, const float* __restrict__ b3,
    const float* __restrict__ sdeg, float* __restrict__ aA,
    float* __restrict__ aB, float* __restrict__ base_out, int N)
{
    __shared__ f16 Blds[24576];   // 48KB

    int tid  = threadIdx.x;
    int lane = tid & 63;
    int wid  = tid >> 6;
    int n0   = (blockIdx.x * 4 + wid) * 16;
    int col  = lane & 15;
    int g    = lane >> 4;
    int nrow = n0 + col;

    f32x4 acc[24];
    #pragma unroll
    for (int i = 0; i < 24; ++i) acc[i] = (f32x4){0.f, 0.f, 0.f, 0.f};

    for (int ks = 0; ks < 4; ++ks) {
        float av[8];
        if (nrow < N) {
            float4 a0 = *(const float4*)&in[(size_t)nrow * D + ks * 32 + g * 8];
            float4 a1 = *(const float4*)&in[(size_t)nrow * D + ks * 32 + g * 8 + 4];
            av[0] = a0.x; av[1] = a0.y; av[2] = a0.z; av[3] = a0.w;
            av[4] = a1.x; av[5] = a1.y; av[6] = a1.z; av[7] = a1.w;
        } else {
            #pragma unroll
            for (int j = 0; j < 8; ++j) av[j] = 0.f;
        }
        f16x8 ahi, alo;
        #pragma unroll
        for (int j = 0; j < 8; ++j) {
            f16 hh = (f16)av[j];
            ahi[j] = hh;
            alo[j] = (f16)(av[j] - (float)hh);
        }

        __syncthreads();
        {
            const f16x8* s4 = (const f16x8*)(Wp + (size_t)ks * 24576);
            f16x8* d4 = (f16x8*)Blds;
            for (int i = tid; i < 3072; i += 256) d4[i] = s4[i];
        }
        __syncthreads();

        #pragma unroll
        for (int mot = 0; mot < 24; ++mot) {
            f16x8 bhi = *(const f16x8*)&Blds[mot * 1024 + lane * 8];
            f16x8 blo = *(const f16x8*)&Blds[mot * 1024 + 512 + lane * 8];
            acc[mot] = __builtin_amdgcn_mfma_f32_16x16x32_f16(ahi, bhi, acc[mot], 0, 0, 0);
            acc[mot] = __builtin_amdgcn_mfma_f32_16x16x32_f16(alo, bhi, acc[mot], 0, 0, 0);
            acc[mot] = __builtin_amdgcn_mfma_f32_16x16x32_f16(ahi, blo, acc[mot], 0, 0, 0);
        }
    }

    #pragma unroll
    for (int ot = 0; ot < 8; ++ot) {
        int o = ot * 16 + col;
        float bi1 = b1[o];
        float bi3 = b3[o];
        float* ah = (o < 64) ? aA : aB;
        int    oh = o & 63;
        #pragma unroll
        for (int r = 0; r < 4; ++r) {
            int node = n0 + g * 4 + r;
            if (node < N) {
                float sv   = sdeg[node];
                float aval = acc[ot][r] + bi1;
                float bval = acc[16 + ot][r] + bi3 - sv * acc[8 + ot][r];
                ah[(size_t)node * 64 + oh]     = aval;
                base_out[(size_t)node * D + o] = bval;
            }
        }
    }
}

// ---------------- CSR aggregate + activation (one 64-feature half) ------

__global__ __launch_bounds__(256) void agg_kernel(
    const float* __restrict__ aH, const float* __restrict__ base,
    const int* __restrict__ row_off, const int2* __restrict__ edge_s,
    float* __restrict__ out, int N, int hofs, int last)
{
    int lane = threadIdx.x & 63;
    int node = blockIdx.x * 4 + (threadIdx.x >> 6);
    if (node >= N) return;

    float acc = base[(size_t)node * D + hofs + lane];
    int beg = row_off[node];
    int end = row_off[node + 1];

    int e = beg;
    if ((e & 1) && e < end) {
        int2 ed = edge_s[e];
        acc = fmaf(__int_as_float(ed.y), aH[(size_t)ed.x * 64 + lane], acc);
        ++e;
    }
    for (; e + 16 <= end; e += 16) {
        int4 ed[8];
        #pragma unroll
        for (int i = 0; i < 8; ++i) ed[i] = *(const int4*)&edge_s[e + i * 2];
        float v[16];
        #pragma unroll
        for (int i = 0; i < 8; ++i) {
            v[2 * i]     = aH[(size_t)ed[i].x * 64 + lane];
            v[2 * i + 1] = aH[(size_t)ed[i].z * 64 + lane];
        }
        #pragma unroll
        for (int i = 0; i < 8; ++i) {
            acc = fmaf(__int_as_float(ed[i].y), v[2 * i], acc);
            acc = fmaf(__int_as_float(ed[i].w), v[2 * i + 1], acc);
        }
    }
    for (; e + 4 <= end; e += 4) {
        int4 e0 = *(const int4*)&edge_s[e];
        int4 e1 = *(const int4*)&edge_s[e + 2];
        float v0 = aH[(size_t)e0.x * 64 + lane];
        float v1 = aH[(size_t)e0.z * 64 + lane];
        float v2 = aH[(size_t)e1.x * 64 + lane];
        float v3 = aH[(size_t)e1.z * 64 + lane];
        acc = fmaf(__int_as_float(e0.y), v0, acc);
        acc = fmaf(__int_as_float(e0.w), v1, acc);
        acc = fmaf(__int_as_float(e1.y), v2, acc);
        acc = fmaf(__int_as_float(e1.w), v3, acc);
    }
    for (; e < end; ++e) {
        int2 ed = edge_s[e];
        acc = fmaf(__int_as_float(ed.y), aH[(size_t)ed.x * 64 + lane], acc);
    }

    acc = acc >= 0.f ? acc : 0.1f * acc;          // leaky relu 0.1
    if (last) acc = 1.f / (1.f + __expf(-acc));   // sigmoid
    out[(size_t)node * D + hofs + lane] = acc;
}

// ---------------- launch ----------------

extern "C" void kernel_launch(void* const* d_in, const int* in_sizes, int n_in,
                              void* d_out, int out_size, void* d_ws, size_t ws_size,
                              hipStream_t stream) {
    const float* x   = (const float*)d_in[0];
    const int*   ei  = (const int*)d_in[1];
    const float* ew  = (const float*)d_in[2];
    const float* iW1 = (const float*)d_in[3];
    const float* ib1 = (const float*)d_in[4];
    const float* iW2 = (const float*)d_in[5];
    const float* iW3 = (const float*)d_in[6];
    const float* ib3 = (const float*)d_in[7];
    const float* mW1 = (const float*)d_in[8];
    const float* mb1 = (const float*)d_in[9];
    const float* mW2 = (const float*)d_in[10];
    const float* mW3 = (const float*)d_in[11];
    const float* mb3 = (const float*)d_in[12];
    const float* oW1 = (const float*)d_in[13];
    const float* ob1 = (const float*)d_in[14];
    const float* oW2 = (const float*)d_in[15];
    const float* oW3 = (const float*)d_in[16];
    const float* ob3 = (const float*)d_in[17];

    int N = in_sizes[0] / D;
    int E = in_sizes[2];
    const int* src = ei;
    const int* dst = ei + E;
    int nchunk = (N + (1 << CSH) - 1) >> CSH;   // 7
    int NBUC   = (N + (1 << BSH) - 1) >> BSH;   // 98

    char* wsp = (char*)d_ws;
    size_t off = 0;
    auto alloc = [&](size_t bytes) -> void* {
        void* p = wsp + off;
        off += (bytes + 255) & ~(size_t)255;
        return p;
    };
    float* h        = (float*)alloc((size_t)N * D * 4);   // aliased by binned
    float* base     = (float*)alloc((size_t)N * D * 4);
    float* aA       = (float*)alloc((size_t)N * 64 * 4);
    float* aB       = (float*)alloc((size_t)N * 64 * 4);
    float* sdeg     = (float*)alloc((size_t)N * 4);
    int*   row_off  = (int*)alloc((size_t)(N + 1) * 4);
    int2*  edge_s   = (int2*)alloc((size_t)E * 8);
    int*   bucketCount  = (int*)alloc((size_t)(NBUC + 1) * 4);
    int*   bucketBase   = (int*)alloc((size_t)(NBUC + 1) * 4);
    int*   bucketCursor = (int*)alloc((size_t)(NBUC + 1) * 4);
    f16*   Wp       = (f16*)alloc((size_t)3 * 98304 * 2);

    int4* binned = (int4*)h;   // binned (E*16B) dead before h's first write

    hipMemsetAsync(bucketCount, 0, (size_t)(NBUC + 1) * 4, stream);

    int ablocks  = (N + 3) / 4;
    int tiles    = (N + 15) / 16;
    int gblocks  = (tiles + 3) / 4;
    int abblocks = (E + 4095) / 4096;

    pack_kernel<<<24, 256, 0, stream>>>(iW1, iW2, iW3, Wp);
    pack_kernel<<<24, 256, 0, stream>>>(mW1, mW2, mW3, Wp + 98304);
    pack_kernel<<<24, 256, 0, stream>>>(oW1, oW2, oW3, Wp + 2 * 98304);

    binA_count<<<abblocks, 256, 0, stream>>>(dst, bucketCount, E);
    bucket_scan<<<1, 64, 0, stream>>>(bucketCount, bucketBase, bucketCursor,
                                      row_off, NBUC, E, N);
    binA_scatter<<<abblocks, 256, 0, stream>>>(src, dst, ew, bucketCursor,
                                               binned, E);
    binB_kernel<<<NBUC, 1024, 0, stream>>>(binned, bucketBase, edge_s,
                                           row_off, sdeg, N, nchunk);

    // layer 1 (in): reads x
    gemm_kernel<<<gblocks, 256, 0, stream>>>(x, Wp, ib1, ib3, sdeg, aA, aB, base, N);
    agg_kernel<<<ablocks, 256, 0, stream>>>(aA, base, row_off, edge_s, h, N, 0, 0);
    agg_kernel<<<ablocks, 256, 0, stream>>>(aB, base, row_off, edge_s, h, N, 64, 0);
    // layers 2..3 (mid, shared weights)
    for (int l = 0; l < 2; ++l) {
        gemm_kernel<<<gblocks, 256, 0, stream>>>(h, Wp + 98304, mb1, mb3, sdeg, aA, aB, base, N);
        agg_kernel<<<ablocks, 256, 0, stream>>>(aA, base, row_off, edge_s, h, N, 0, 0);
        agg_kernel<<<ablocks, 256, 0, stream>>>(aB, base, row_off, edge_s, h, N, 64, 0);
    }
    // layer 4 (out) -> d_out with sigmoid
    gemm_kernel<<<gblocks, 256, 0, stream>>>(h, Wp + 2 * 98304, ob1, ob3, sdeg, aA, aB, base, N);
    agg_kernel<<<ablocks, 256, 0, stream>>>(aA, base, row_off, edge_s, (float*)d_out, N, 0, 1);
    agg_kernel<<<ablocks, 256, 0, stream>>>(aB, base, row_off, edge_s, (float*)d_out, N, 64, 1);
}

// Round 10
// 679.866 us; speedup vs baseline: 1.7774x; 1.0698x over previous
//
#include <hip/hip_runtime.h>
#include <hip/hip_fp16.h>
#include <math.h>

#define D 128
#define CSH 13      // src-chunk shift: 8192 nodes/chunk -> 7 chunks at N=50000
#define BSH 9       // dst-bucket shift: 512 nodes/bucket -> 98 buckets
#define NB_MAX 128

typedef _Float16 f16;
typedef __attribute__((ext_vector_type(8))) _Float16 f16x8;
typedef __attribute__((ext_vector_type(4))) float f32x4;

// ---------------- preprocessing: two-level binning ----------------

__global__ __launch_bounds__(256) void binA_count(
    const int* __restrict__ dst, int* __restrict__ bucketCount, int E)
{
    __shared__ int hist[NB_MAX];
    int tid = threadIdx.x;
    if (tid < NB_MAX) hist[tid] = 0;
    __syncthreads();
    int base = blockIdx.x * 4096;
    for (int i = tid; i < 4096; i += 256) {
        int e = base + i;
        if (e < E) atomicAdd(&hist[dst[e] >> BSH], 1);
    }
    __syncthreads();
    if (tid < NB_MAX && hist[tid]) atomicAdd(&bucketCount[tid], hist[tid]);
}

__global__ void bucket_scan(
    const int* __restrict__ bucketCount, int* __restrict__ bucketBase,
    int* __restrict__ bucketCursor, int* __restrict__ row_off,
    int NBUC, int E, int N)
{
    if (threadIdx.x == 0 && blockIdx.x == 0) {
        int p = 0;
        for (int b = 0; b < NBUC; ++b) {
            bucketBase[b] = p; bucketCursor[b] = p; p += bucketCount[b];
        }
        bucketBase[NBUC] = p;
        row_off[N] = E;
    }
}

__global__ __launch_bounds__(256) void binA_scatter(
    const int* __restrict__ src, const int* __restrict__ dst,
    const float* __restrict__ ew, int* __restrict__ bucketCursor,
    int4* __restrict__ binned, int E)
{
    __shared__ int hist[NB_MAX], off[NB_MAX], cbase[NB_MAX];
    int tid = threadIdx.x;
    if (tid < NB_MAX) { hist[tid] = 0; off[tid] = 0; }
    __syncthreads();
    int base = blockIdx.x * 4096;
    for (int i = tid; i < 4096; i += 256) {
        int e = base + i;
        if (e < E) atomicAdd(&hist[dst[e] >> BSH], 1);
    }
    __syncthreads();
    if (tid < NB_MAX && hist[tid])
        cbase[tid] = atomicAdd(&bucketCursor[tid], hist[tid]);
    __syncthreads();
    for (int i = tid; i < 4096; i += 256) {
        int e = base + i;
        if (e < E) {
            int d = dst[e];
            int b = d >> BSH;
            int pos = cbase[b] + atomicAdd(&off[b], 1);
            binned[pos] = make_int4(src[e], __float_as_int(ew[e]), d, 0);
        }
    }
}

__global__ __launch_bounds__(1024) void binB_kernel(
    const int4* __restrict__ binned, const int* __restrict__ bucketBase,
    int2* __restrict__ edge_s, int* __restrict__ row_off,
    float* __restrict__ sdeg, int N, int nchunk)
{
    __shared__ int hist[4096];
    __shared__ int cur[4096];
    __shared__ float sdl[512];
    __shared__ int wsum[16];

    int b    = blockIdx.x;
    int tid  = threadIdx.x;
    int ebeg = bucketBase[b], eend = bucketBase[b + 1];
    int node0 = b << BSH;
    int nib   = min(512, N - node0);

    for (int i = tid; i < 4096; i += 1024) hist[i] = 0;
    for (int i = tid; i < 512; i += 1024) sdl[i] = 0.f;
    __syncthreads();

    for (int e = ebeg + tid; e < eend; e += 1024) {
        int4 ed = binned[e];
        int dl = ed.z - node0;
        int ch = ((unsigned)ed.x) >> CSH;
        atomicAdd(&hist[dl * nchunk + ch], 1);
        atomicAdd(&sdl[dl], __int_as_float(ed.y));
    }
    __syncthreads();

    int t4 = tid * 4;
    int h0 = hist[t4], h1 = hist[t4 + 1], h2 = hist[t4 + 2], h3 = hist[t4 + 3];
    int sum = h0 + h1 + h2 + h3;
    int lane = tid & 63, wid = tid >> 6;
    int x = sum;
    #pragma unroll
    for (int o = 1; o < 64; o <<= 1) { int t = __shfl_up(x, o); if (lane >= o) x += t; }
    if (lane == 63) wsum[wid] = x;
    __syncthreads();
    if (tid < 16) {
        int y = wsum[tid];
        #pragma unroll
        for (int o = 1; o < 16; o <<= 1) { int t = __shfl_up(y, o, 16); if (tid >= o) y += t; }
        wsum[tid] = y;
    }
    __syncthreads();
    int excl = (wid ? wsum[wid - 1] : 0) + x - sum;
    cur[t4] = excl; cur[t4 + 1] = excl + h0;
    cur[t4 + 2] = excl + h0 + h1; cur[t4 + 3] = excl + h0 + h1 + h2;
    __syncthreads();

    for (int dl = tid; dl < nib; dl += 1024) {
        row_off[node0 + dl] = ebeg + cur[dl * nchunk];
        sdeg[node0 + dl]    = sdl[dl];
    }
    __syncthreads();

    for (int e = ebeg + tid; e < eend; e += 1024) {
        int4 ed = binned[e];
        int dl = ed.z - node0;
        int ch = ((unsigned)ed.x) >> CSH;
        int pos = ebeg + atomicAdd(&cur[dl * nchunk + ch], 1);
        edge_s[pos] = make_int2(ed.x, ed.y);
    }
}

// ---------------- W pack: f32 -> fp16 hi/lo in MFMA B-fragment order -----
__global__ __launch_bounds__(256) void pack_kernel(
    const float* __restrict__ W1, const float* __restrict__ W2,
    const float* __restrict__ W3, f16* __restrict__ Wp)
{
    int idx = blockIdx.x * 256 + threadIdx.x;   // 6144 total
    if (idx >= 6144) return;
    int lane = idx & 63;
    int t    = idx >> 6;       // 0..95
    int ks   = t & 3;
    int mot  = t >> 2;         // 0..23
    int m    = mot >> 3;
    int ot   = mot & 7;
    const float* W = (m == 0) ? W1 : (m == 1) ? W2 : W3;
    int o  = ot * 16 + (lane & 15);
    int kb = ks * 32 + (lane >> 4) * 8;
    f16x8 hi, lo;
    #pragma unroll
    for (int j = 0; j < 8; ++j) {
        float v = W[(size_t)o * D + kb + j];
        f16 hh = (f16)v;
        hi[j] = hh;
        lo[j] = (f16)(v - (float)hh);
    }
    size_t base = (size_t)ks * 24576 + (size_t)mot * 1024 + (size_t)lane * 8;
    *(f16x8*)&Wp[base]       = hi;
    *(f16x8*)&Wp[base + 512] = lo;
}

// ---------------- MFMA fused 3-matmul, W in registers --------------------
// Each wave owns 2 out-tiles (ot = 2*wid, 2*wid+1) x 3 matrices; W frags
// (48 f16x8 = 192 VGPR) loaded ONCE per block. No LDS, no barriers. Block
// strides over 16-node tiles; 72 reg-operand MFMAs per tile, 6 indep acc
// chains. 4 waves of a block share A tile via L1.

__global__ __launch_bounds__(256, 2) void gemm_kernel(
    const float* __restrict__ in, const f16* __restrict__ Wp,
    const float* __restrict__ b1, const float* __restrict__ b3,
    const float* __restrict__ sdeg, float* __restrict__ aA,
    float* __restrict__ aB, float* __restrict__ base_out,
    int N, int ntiles, int gridb)
{
    int tid  = threadIdx.x;
    int lane = tid & 63;
    int wid  = tid >> 6;
    int col  = lane & 15;
    int g    = lane >> 4;

    // W fragments: [m][oti][ks][hi/lo]
    f16x8 w[3][2][4][2];
    #pragma unroll
    for (int m = 0; m < 3; ++m)
        #pragma unroll
        for (int oti = 0; oti < 2; ++oti) {
            int mot = m * 8 + wid * 2 + oti;
            #pragma unroll
            for (int ks = 0; ks < 4; ++ks) {
                const f16* p = Wp + (size_t)ks * 24576 + (size_t)mot * 1024 + (size_t)lane * 8;
                w[m][oti][ks][0] = *(const f16x8*)p;
                w[m][oti][ks][1] = *(const f16x8*)(p + 512);
            }
        }

    float bi1[2], bi3[2];
    #pragma unroll
    for (int oti = 0; oti < 2; ++oti) {
        int o = (wid * 2 + oti) * 16 + col;
        bi1[oti] = b1[o];
        bi3[oti] = b3[o];
    }

    for (int t = blockIdx.x; t < ntiles; t += gridb) {
        int n0   = t * 16;
        int nrow = n0 + col;

        f32x4 acc[3][2];
        #pragma unroll
        for (int m = 0; m < 3; ++m)
            #pragma unroll
            for (int oti = 0; oti < 2; ++oti)
                acc[m][oti] = (f32x4){0.f, 0.f, 0.f, 0.f};

        #pragma unroll
        for (int ks = 0; ks < 4; ++ks) {
            float av[8];
            if (nrow < N) {
                float4 a0 = *(const float4*)&in[(size_t)nrow * D + ks * 32 + g * 8];
                float4 a1 = *(const float4*)&in[(size_t)nrow * D + ks * 32 + g * 8 + 4];
                av[0] = a0.x; av[1] = a0.y; av[2] = a0.z; av[3] = a0.w;
                av[4] = a1.x; av[5] = a1.y; av[6] = a1.z; av[7] = a1.w;
            } else {
                #pragma unroll
                for (int j = 0; j < 8; ++j) av[j] = 0.f;
            }
            f16x8 ahi, alo;
            #pragma unroll
            for (int j = 0; j < 8; ++j) {
                f16 hh = (f16)av[j];
                ahi[j] = hh;
                alo[j] = (f16)(av[j] - (float)hh);
            }
            #pragma unroll
            for (int m = 0; m < 3; ++m)
                #pragma unroll
                for (int oti = 0; oti < 2; ++oti) {
                    acc[m][oti] = __builtin_amdgcn_mfma_f32_16x16x32_f16(ahi, w[m][oti][ks][0], acc[m][oti], 0, 0, 0);
                    acc[m][oti] = __builtin_amdgcn_mfma_f32_16x16x32_f16(alo, w[m][oti][ks][0], acc[m][oti], 0, 0, 0);
                    acc[m][oti] = __builtin_amdgcn_mfma_f32_16x16x32_f16(ahi, w[m][oti][ks][1], acc[m][oti], 0, 0, 0);
                }
        }

        // epilogue: o = (2*wid+oti)*16 + col; node = n0 + g*4 + r
        float* ah = (wid < 2) ? aA : aB;
        #pragma unroll
        for (int oti = 0; oti < 2; ++oti) {
            int o  = (wid * 2 + oti) * 16 + col;
            int oh = o & 63;
            #pragma unroll
            for (int r = 0; r < 4; ++r) {
                int node = n0 + g * 4 + r;
                if (node < N) {
                    float sv   = sdeg[node];
                    float aval = acc[0][oti][r] + bi1[oti];
                    float bval = acc[2][oti][r] + bi3[oti] - sv * acc[1][oti][r];
                    ah[(size_t)node * 64 + oh]     = aval;
                    base_out[(size_t)node * D + o] = bval;
                }
            }
        }
    }
}

// ---------------- CSR aggregate + activation (both halves, one kernel) ---
// 4 waves: (node, half) = (blk*2 + (wid>>1), wid&1). Waves of one node share
// edge_s/row_off via L1.

__global__ __launch_bounds__(256) void agg_kernel(
    const float* __restrict__ aA, const float* __restrict__ aB,
    const float* __restrict__ base, const int* __restrict__ row_off,
    const int2* __restrict__ edge_s, float* __restrict__ out, int N, int last)
{
    int lane = threadIdx.x & 63;
    int wid  = threadIdx.x >> 6;
    int node = blockIdx.x * 2 + (wid >> 1);
    int half = wid & 1;
    if (node >= N) return;
    const float* aH = half ? aB : aA;
    int hofs = half << 6;

    float acc = base[(size_t)node * D + hofs + lane];
    int beg = row_off[node];
    int end = row_off[node + 1];

    int e = beg;
    if ((e & 1) && e < end) {
        int2 ed = edge_s[e];
        acc = fmaf(__int_as_float(ed.y), aH[(size_t)ed.x * 64 + lane], acc);
        ++e;
    }
    for (; e + 16 <= end; e += 16) {
        int4 ed[8];
        #pragma unroll
        for (int i = 0; i < 8; ++i) ed[i] = *(const int4*)&edge_s[e + i * 2];
        float v[16];
        #pragma unroll
        for (int i = 0; i < 8; ++i) {
            v[2 * i]     = aH[(size_t)ed[i].x * 64 + lane];
            v[2 * i + 1] = aH[(size_t)ed[i].z * 64 + lane];
        }
        #pragma unroll
        for (int i = 0; i < 8; ++i) {
            acc = fmaf(__int_as_float(ed[i].y), v[2 * i], acc);
            acc = fmaf(__int_as_float(ed[i].w), v[2 * i + 1], acc);
        }
    }
    for (; e + 4 <= end; e += 4) {
        int4 e0 = *(const int4*)&edge_s[e];
        int4 e1 = *(const int4*)&edge_s[e + 2];
        float v0 = aH[(size_t)e0.x * 64 + lane];
        float v1 = aH[(size_t)e0.z * 64 + lane];
        float v2 = aH[(size_t)e1.x * 64 + lane];
        float v3 = aH[(size_t)e1.z * 64 + lane];
        acc = fmaf(__int_as_float(e0.y), v0, acc);
        acc = fmaf(__int_as_float(e0.w), v1, acc);
        acc = fmaf(__int_as_float(e1.y), v2, acc);
        acc = fmaf(__int_as_float(e1.w), v3, acc);
    }
    for (; e < end; ++e) {
        int2 ed = edge_s[e];
        acc = fmaf(__int_as_float(ed.y), aH[(size_t)ed.x * 64 + lane], acc);
    }

    acc = acc >= 0.f ? acc : 0.1f * acc;          // leaky relu 0.1
    if (last) acc = 1.f / (1.f + __expf(-acc));   // sigmoid
    out[(size_t)node * D + hofs + lane] = acc;
}

// ---------------- launch ----------------

extern "C" void kernel_launch(void* const* d_in, const int* in_sizes, int n_in,
                              void* d_out, int out_size, void* d_ws, size_t ws_size,
                              hipStream_t stream) {
    const float* x   = (const float*)d_in[0];
    const int*   ei  = (const int*)d_in[1];
    const float* ew  = (const float*)d_in[2];
    const float* iW1 = (const float*)d_in[3];
    const float* ib1 = (const float*)d_in[4];
    const float* iW2 = (const float*)d_in[5];
    const float* iW3 = (const float*)d_in[6];
    const float* ib3 = (const float*)d_in[7];
    const float* mW1 = (const float*)d_in[8];
    const float* mb1 = (const float*)d_in[9];
    const float* mW2 = (const float*)d_in[10];
    const float* mW3 = (const float*)d_in[11];
    const float* mb3 = (const float*)d_in[12];
    const float* oW1 = (const float*)d_in[13];
    const float* ob1 = (const float*)d_in[14];
    const float* oW2 = (const float*)d_in[15];
    const float* oW3 = (const float*)d_in[16];
    const float* ob3 = (const float*)d_in[17];

    int N = in_sizes[0] / D;
    int E = in_sizes[2];
    const int* src = ei;
    const int* dst = ei + E;
    int nchunk = (N + (1 << CSH) - 1) >> CSH;   // 7
    int NBUC   = (N + (1 << BSH) - 1) >> BSH;   // 98

    char* wsp = (char*)d_ws;
    size_t off = 0;
    auto alloc = [&](size_t bytes) -> void* {
        void* p = wsp + off;
        off += (bytes + 255) & ~(size_t)255;
        return p;
    };
    float* h        = (float*)alloc((size_t)N * D * 4);   // aliased by binned
    float* base     = (float*)alloc((size_t)N * D * 4);
    float* aA       = (float*)alloc((size_t)N * 64 * 4);
    float* aB       = (float*)alloc((size_t)N * 64 * 4);
    float* sdeg     = (float*)alloc((size_t)N * 4);
    int*   row_off  = (int*)alloc((size_t)(N + 1) * 4);
    int2*  edge_s   = (int2*)alloc((size_t)E * 8);
    int*   bucketCount  = (int*)alloc((size_t)(NBUC + 1) * 4);
    int*   bucketBase   = (int*)alloc((size_t)(NBUC + 1) * 4);
    int*   bucketCursor = (int*)alloc((size_t)(NBUC + 1) * 4);
    f16*   Wp       = (f16*)alloc((size_t)3 * 98304 * 2);

    int4* binned = (int4*)h;

    hipMemsetAsync(bucketCount, 0, (size_t)(NBUC + 1) * 4, stream);

    int aggblocks = (N + 1) / 2;
    int ntiles    = (N + 15) / 16;
    int gridb     = 512;
    int abblocks  = (E + 4095) / 4096;

    pack_kernel<<<24, 256, 0, stream>>>(iW1, iW2, iW3, Wp);
    pack_kernel<<<24, 256, 0, stream>>>(mW1, mW2, mW3, Wp + 98304);
    pack_kernel<<<24, 256, 0, stream>>>(oW1, oW2, oW3, Wp + 2 * 98304);

    binA_count<<<abblocks, 256, 0, stream>>>(dst, bucketCount, E);
    bucket_scan<<<1, 64, 0, stream>>>(bucketCount, bucketBase, bucketCursor,
                                      row_off, NBUC, E, N);
    binA_scatter<<<abblocks, 256, 0, stream>>>(src, dst, ew, bucketCursor,
                                               binned, E);
    binB_kernel<<<NBUC, 1024, 0, stream>>>(binned, bucketBase, edge_s,
                                           row_off, sdeg, N, nchunk);

    // layer 1 (in): reads x
    gemm_kernel<<<gridb, 256, 0, stream>>>(x, Wp, ib1, ib3, sdeg, aA, aB, base, N, ntiles, gridb);
    agg_kernel<<<aggblocks, 256, 0, stream>>>(aA, aB, base, row_off, edge_s, h, N, 0);
    // layers 2..3 (mid, shared weights)
    for (int l = 0; l < 2; ++l) {
        gemm_kernel<<<gridb, 256, 0, stream>>>(h, Wp + 98304, mb1, mb3, sdeg, aA, aB, base, N, ntiles, gridb);
        agg_kernel<<<aggblocks, 256, 0, stream>>>(aA, aB, base, row_off, edge_s, h, N, 0);
    }
    // layer 4 (out) -> d_out with sigmoid
    gemm_kernel<<<gridb, 256, 0, stream>>>(h, Wp + 2 * 98304, ob1, ob3, sdeg, aA, aB, base, N, ntiles, gridb);
    agg_kernel<<<aggblocks, 256, 0, stream>>>(aA, aB, base, row_off, edge_s, (float*)d_out, N, 1);
}